// Round 2
// baseline (332.821 us; speedup 1.0000x reference)
//
#include <hip/hip_runtime.h>

// Problem dims
#define NN 64
#define EE 128
#define GG 4
#define D0 9
#define EDIM 4
#define H1 2000
#define H2 500
#define H3 100
#define FF1 1000
#define FF2 100
#define FF3 50

// Workspace layout (floats)
#define OFF_ACH  0         // 6*64*64 = 24576   per-channel adjacency A_d[v][u]
#define OFF_Y    24576     // 64*54   = 3456    folded layer-1 input
#define OFF_P1   28032     // 64*2000 = 128000  relu(pre1)
#define OFF_Q    156032    // 64*12000= 768000  Q2f (Q3f 64*3000 overlays)
#define OFF_PART 924032    // 50*64*500 = 1600000 partials (L3 50*64*100 overlays)
#define OFF_P2   2524032   // 64*500  = 32000   relu(pre2)
#define OFF_PRE3 2556032   // 64*100  = 6400
#define OFF_F1   2562432   // 4*1000  = 4000
#define OFF_F2   2566432   // 4*100   = 400
// total 2566832 floats = 10.3 MB

// ---------------------------------------------------------------------------
// async global->LDS 16B copy. LDS dest is wave-uniform base + lane*16;
// global source address is per-lane. Exec-masked lanes skip their write.
// ---------------------------------------------------------------------------
__device__ __forceinline__ void gl2lds16(const float* g, float* l) {
    __builtin_amdgcn_global_load_lds(
        (const __attribute__((address_space(1))) unsigned int*)g,
        (__attribute__((address_space(3))) unsigned int*)l,
        16, 0, 0);
}

__device__ __forceinline__ float4 ldf4(const float* p) {
    return *(const float4*)p;
}

// ---------------------------------------------------------------------------
// K0: block0 = Ach (per-channel 64x64 adjacency), block1 = Y, block2 = f2=c2
// ---------------------------------------------------------------------------
__global__ __launch_bounds__(256) void k_init(
    const float* __restrict__ x, const int* __restrict__ edge_index,
    const float* __restrict__ edge_attr, const float* __restrict__ c2,
    float* __restrict__ ws)
{
    const int b = blockIdx.x, tid = threadIdx.x;
    if (b == 0) {
        // Ach[d][t][s]: d<4 edge_attr scatter; d=4 edge count; d=5 identity
        float* A = ws + OFF_ACH;
        for (int i = tid; i < 6 * NN * NN; i += 256) A[i] = 0.f;
        __syncthreads();
        if (tid < EE) {
            int s = edge_index[tid];
            int t = edge_index[EE + tid];
            #pragma unroll
            for (int d = 0; d < 4; ++d)
                atomicAdd(A + d * 4096 + t * 64 + s, edge_attr[tid * 4 + d]);
            atomicAdd(A + 4 * 4096 + t * 64 + s, 1.0f);
        }
        if (tid < NN) A[5 * 4096 + tid * 64 + tid] = 1.0f;
    } else if (b == 1) {
        // Y[u, d*9+i]: d<4 edge-weighted scatter of x[src], d=4 edge-count
        // scatter, d=5 identity (x itself)
        __shared__ float Ys[NN * 54];
        for (int i = tid; i < NN * 54; i += 256) Ys[i] = 0.f;
        __syncthreads();
        if (tid < EE) {
            int s = edge_index[tid];
            int t = edge_index[EE + tid];
            float ea[4];
            #pragma unroll
            for (int d = 0; d < 4; ++d) ea[d] = edge_attr[tid * 4 + d];
            #pragma unroll
            for (int i = 0; i < D0; ++i) {
                float xv = x[s * D0 + i];
                #pragma unroll
                for (int d = 0; d < 4; ++d)
                    atomicAdd(&Ys[t * 54 + d * 9 + i], ea[d] * xv);
                atomicAdd(&Ys[t * 54 + 36 + i], xv);
            }
        }
        if (tid < NN) {
            #pragma unroll
            for (int i = 0; i < D0; ++i) Ys[tid * 54 + 45 + i] = x[tid * D0 + i];
        }
        __syncthreads();
        for (int i = tid; i < NN * 54; i += 256) ws[OFF_Y + i] = Ys[i];
    } else {
        for (int i = tid; i < GG * FF2; i += 256) ws[OFF_F2 + i] = c2[i % FF2];
    }
}

// ---------------------------------------------------------------------------
// K1: P1[64x2000] = relu(b1 + Y[64x54] @ Wall1[54x2000])
// ---------------------------------------------------------------------------
__global__ __launch_bounds__(256) void k_lin1(
    const float* __restrict__ Yw,
    const float* __restrict__ We1, const float* __restrict__ be1,
    const float* __restrict__ root1, const float* __restrict__ b1,
    float* __restrict__ pre1)
{
    const int tid = threadIdx.x;
    const int tx = tid & 15, ty = tid >> 4;
    const int o0 = blockIdx.x * 64;
    const int w = min(64, H1 - o0);

    __shared__ float Ys[64 * 56];
    __shared__ __align__(16) float Bs[54 * 64];

    for (int i = tid; i < 64 * 54; i += 256) {
        int u = i / 54, r = i - u * 54;
        Ys[u * 56 + r] = Yw[i];
    }
    for (int i = tid; i < 54 * 64; i += 256) {
        int r = i >> 6, c = i & 63;
        int d = r / 9, ii = r - d * 9;
        const float* rowp = ((d < 4) ? (We1 + d * (D0 * H1))
                                     : ((d == 4) ? be1 : root1)) + ii * H1;
        Bs[r * 64 + c] = (c < w) ? rowp[o0 + c] : 0.f;
    }
    __syncthreads();

    float acc[4][4] = {};
    #pragma unroll 6
    for (int r = 0; r < 54; ++r) {
        float a0 = Ys[(ty * 4 + 0) * 56 + r];
        float a1 = Ys[(ty * 4 + 1) * 56 + r];
        float a2 = Ys[(ty * 4 + 2) * 56 + r];
        float a3 = Ys[(ty * 4 + 3) * 56 + r];
        const float4 bv = *(const float4*)&Bs[r * 64 + tx * 4];
        acc[0][0] += a0 * bv.x; acc[0][1] += a0 * bv.y; acc[0][2] += a0 * bv.z; acc[0][3] += a0 * bv.w;
        acc[1][0] += a1 * bv.x; acc[1][1] += a1 * bv.y; acc[1][2] += a1 * bv.z; acc[1][3] += a1 * bv.w;
        acc[2][0] += a2 * bv.x; acc[2][1] += a2 * bv.y; acc[2][2] += a2 * bv.z; acc[2][3] += a2 * bv.w;
        acc[3][0] += a3 * bv.x; acc[3][1] += a3 * bv.y; acc[3][2] += a3 * bv.z; acc[3][3] += a3 * bv.w;
    }
    #pragma unroll
    for (int i = 0; i < 4; ++i) {
        int u = ty * 4 + i;
        #pragma unroll
        for (int jj = 0; jj < 4; ++jj) {
            int j = o0 + tx * 4 + jj;
            if (j < H1) {
                float v = b1[j] + acc[i][jj];
                pre1[u * H1 + j] = v > 0.f ? v : 0.f;
            }
        }
    }
}

// ---------------------------------------------------------------------------
// k_q: Qf[v, d*Kd + k] = sum_u Ach[d][v][u] * P[u][k]
//   block = (d, kt): 128 cols; 256 thr = 2 v-halves x 128 cols; acc[32].
//   A read with wave-uniform indices (readfirstlane base -> s_load path).
// ---------------------------------------------------------------------------
template<int Kd, int KTOT, int NKT>
__global__ __launch_bounds__(256) void k_q(
    const float* __restrict__ Ach, const float* __restrict__ P,
    float* __restrict__ Qf)
{
    const int bx = blockIdx.x;
    const int d = bx / NKT, kt = bx % NKT;
    const int k0 = kt * 128;
    const int tid = threadIdx.x;
    const int kk = tid & 127;
    const int k = k0 + kk;
    const int vh = __builtin_amdgcn_readfirstlane(tid >> 7);
    const int nf4 = min(128, Kd - k0) >> 2;

    __shared__ __align__(16) float Pl[64 * 128];
    for (int i4 = tid; i4 < 64 * 32; i4 += 256) {
        int u = i4 >> 5, c4 = i4 & 31;
        if (c4 < nf4)
            *(float4*)&Pl[u * 128 + c4 * 4] = ldf4(P + u * Kd + k0 + c4 * 4);
    }
    __syncthreads();

    const float* Ad = Ach + d * 4096 + vh * (32 * 64);
    float acc[32] = {};
    #pragma unroll 4
    for (int u4 = 0; u4 < 16; ++u4) {
        float p0 = Pl[(u4 * 4 + 0) * 128 + kk];
        float p1 = Pl[(u4 * 4 + 1) * 128 + kk];
        float p2 = Pl[(u4 * 4 + 2) * 128 + kk];
        float p3 = Pl[(u4 * 4 + 3) * 128 + kk];
        #pragma unroll
        for (int r = 0; r < 32; ++r) {
            float4 a = ldf4(Ad + r * 64 + u4 * 4);
            acc[r] += a.x * p0 + a.y * p1 + a.z * p2 + a.w * p3;
        }
    }
    if (k < Kd) {
        #pragma unroll
        for (int r = 0; r < 32; ++r)
            Qf[(vh * 32 + r) * KTOT + d * Kd + k] = acc[r];
    }
}

// ---------------------------------------------------------------------------
// k_split: part[s][64][M] (col stripe o0..o0+31) = Qf[64 x span] @ Wstk
//   Wstk rows kg: [0,T1) We (flat: section stride = row-stride product),
//   [T1,T2) be, [T2,KTOT) root. NON-ATOMIC output (slice per K-span).
//   BN=32, KC=20 (80B A rows -> 2-way LDS alias max), double-buffered
//   global_load_lds staging, one barrier per iter.
// ---------------------------------------------------------------------------
template<int M, int OT, int S, int ITERS, int T1, int T2>
__global__ __launch_bounds__(256) void k_split(
    const float* __restrict__ Qf, const float* __restrict__ We,
    const float* __restrict__ be, const float* __restrict__ root,
    float* __restrict__ part)
{
    constexpr int KC = 20, BN = 32;
    constexpr int KTOT = S * ITERS * KC;
    const int b = blockIdx.x;
    const int s = b % S, ot = b / S;
    const int o0 = ot * BN;
    const int tid = threadIdx.x;
    const int tx = tid & 7, ty = tid >> 3;      // 8 col-quads x 32 row-pairs
    const int wv = tid >> 6, ln = tid & 63;
    const int kbase = s * (KC * ITERS);

    __shared__ __align__(16) float As[2][64 * KC];   // [row][k]
    __shared__ __align__(16) float Bs[2][KC * BN];   // [k][col]

    auto stage = [&](int bf, int kb) {
        // A: 1280 floats = 5 x 1KB chunks
        for (int c = wv; c < 5; c += 4) {
            int f = c * 256 + ln * 4;
            int r = f / KC, kkk = f - r * KC;
            gl2lds16(Qf + r * KTOT + kb + kkk, &As[bf][c * 256]);
        }
        // B: 640 floats = 2 full chunks + 1 half chunk (lanes < 32)
        for (int c = wv; c < 3; c += 4) {
            int f = c * 256 + ln * 4;
            int krow = (f >> 5) & 31, col = f & 31;
            int kg = kb + krow;
            const float* bp = (kg < T1) ? (We + (long long)kg * M)
                            : (kg < T2) ? (be + (long long)(kg - T1) * M)
                                        : (root + (long long)(kg - T2) * M);
            if (f < KC * BN && (o0 + col) < M)
                gl2lds16(bp + o0 + col, &Bs[bf][c * 256]);
        }
    };

    float acc[2][4] = {};
    stage(0, kbase);
    __syncthreads();

    for (int it = 0; it < ITERS; ++it) {
        if (it + 1 < ITERS) stage((it + 1) & 1, kbase + (it + 1) * KC);
        const float* Ab = As[it & 1];
        const float* Bb = Bs[it & 1];
        #pragma unroll
        for (int k4 = 0; k4 < KC / 4; ++k4) {
            float4 a0 = ldf4(&Ab[(ty * 2 + 0) * KC + k4 * 4]);
            float4 a1 = ldf4(&Ab[(ty * 2 + 1) * KC + k4 * 4]);
            float4 b0 = ldf4(&Bb[(k4 * 4 + 0) * BN + tx * 4]);
            float4 b1 = ldf4(&Bb[(k4 * 4 + 1) * BN + tx * 4]);
            float4 b2 = ldf4(&Bb[(k4 * 4 + 2) * BN + tx * 4]);
            float4 b3 = ldf4(&Bb[(k4 * 4 + 3) * BN + tx * 4]);
            acc[0][0] += a0.x * b0.x; acc[0][1] += a0.x * b0.y; acc[0][2] += a0.x * b0.z; acc[0][3] += a0.x * b0.w;
            acc[0][0] += a0.y * b1.x; acc[0][1] += a0.y * b1.y; acc[0][2] += a0.y * b1.z; acc[0][3] += a0.y * b1.w;
            acc[0][0] += a0.z * b2.x; acc[0][1] += a0.z * b2.y; acc[0][2] += a0.z * b2.z; acc[0][3] += a0.z * b2.w;
            acc[0][0] += a0.w * b3.x; acc[0][1] += a0.w * b3.y; acc[0][2] += a0.w * b3.z; acc[0][3] += a0.w * b3.w;
            acc[1][0] += a1.x * b0.x; acc[1][1] += a1.x * b0.y; acc[1][2] += a1.x * b0.z; acc[1][3] += a1.x * b0.w;
            acc[1][0] += a1.y * b1.x; acc[1][1] += a1.y * b1.y; acc[1][2] += a1.y * b1.z; acc[1][3] += a1.y * b1.w;
            acc[1][0] += a1.z * b2.x; acc[1][1] += a1.z * b2.y; acc[1][2] += a1.z * b2.z; acc[1][3] += a1.z * b2.w;
            acc[1][0] += a1.w * b3.x; acc[1][1] += a1.w * b3.y; acc[1][2] += a1.w * b3.z; acc[1][3] += a1.w * b3.w;
        }
        __syncthreads();   // drains staged loads; protects buffer reuse
    }

    float* dst = part + s * (64 * M);
    #pragma unroll
    for (int i = 0; i < 2; ++i) {
        int u = ty * 2 + i;
        #pragma unroll
        for (int jj = 0; jj < 4; ++jj) {
            int j = o0 + tx * 4 + jj;
            if (j < M) dst[u * M + j] = acc[i][jj];
        }
    }
}

// ---------------------------------------------------------------------------
// k_red2: P2 = relu(b2 + sum_s part[s])   [64x500], 50 slices
// ---------------------------------------------------------------------------
__global__ __launch_bounds__(256) void k_red2(
    const float* __restrict__ part, const float* __restrict__ b2,
    float* __restrict__ P2)
{
    int i4 = blockIdx.x * 256 + threadIdx.x;
    if (i4 >= (64 * 500) / 4) return;
    int o = (i4 * 4) % 500;
    float4 acc = ldf4(b2 + o);
    #pragma unroll 10
    for (int s = 0; s < 50; ++s) {
        float4 v = ldf4(part + s * 32000 + i4 * 4);
        acc.x += v.x; acc.y += v.y; acc.z += v.z; acc.w += v.w;
    }
    acc.x = fmaxf(acc.x, 0.f); acc.y = fmaxf(acc.y, 0.f);
    acc.z = fmaxf(acc.z, 0.f); acc.w = fmaxf(acc.w, 0.f);
    *(float4*)(P2 + i4 * 4) = acc;
}

// ---------------------------------------------------------------------------
// k_red3: pre3 = b3 + sum_s part[s]   [64x100], 50 slices (raw; relu in head1)
// ---------------------------------------------------------------------------
__global__ __launch_bounds__(256) void k_red3(
    const float* __restrict__ part, const float* __restrict__ b3,
    float* __restrict__ pre3)
{
    int i4 = blockIdx.x * 256 + threadIdx.x;
    if (i4 >= (64 * 100) / 4) return;
    int o = (i4 * 4) % 100;
    float4 acc = ldf4(b3 + o);
    #pragma unroll 10
    for (int s = 0; s < 50; ++s) {
        float4 v = ldf4(part + s * 6400 + i4 * 4);
        acc.x += v.x; acc.y += v.y; acc.z += v.z; acc.w += v.w;
    }
    *(float4*)(pre3 + i4 * 4) = acc;
}

// ---------------------------------------------------------------------------
// K6: per (gi, o-tile) block: g[gi] = segment-sum relu(pre3), then
//     f1[gi, o-tile] = relu(c1 + g @ W1)
// ---------------------------------------------------------------------------
__global__ __launch_bounds__(256) void k_head1(
    const float* __restrict__ pre3, const int* __restrict__ batch,
    const float* __restrict__ W1, const float* __restrict__ c1,
    float* __restrict__ f1)
{
    const int gi = blockIdx.x >> 4;
    const int jt = blockIdx.x & 15;
    const int o0 = jt * 64;
    const int tid = threadIdx.x;
    __shared__ int   bsh[NN];
    __shared__ float gs[H3];
    __shared__ float red[4 * 64];

    if (tid < NN) bsh[tid] = batch[tid];
    __syncthreads();
    for (int d = tid; d < H3; d += 256) {
        float acc = 0.f;
        #pragma unroll
        for (int v = 0; v < NN; ++v) {
            float h = pre3[v * H3 + d];
            h = h > 0.f ? h : 0.f;
            acc += (bsh[v] == gi) ? h : 0.f;
        }
        gs[d] = acc;
    }
    __syncthreads();
    const int jj = tid & 63, kq = tid >> 6;
    const int oc = min(o0 + jj, FF1 - 1);
    float p = 0.f;
    #pragma unroll
    for (int k = kq * 25; k < kq * 25 + 25; ++k)
        p += gs[k] * W1[k * FF1 + oc];
    red[kq * 64 + jj] = p;
    __syncthreads();
    if (tid < 64) {
        int o = o0 + tid;
        if (o < FF1) {
            float v = c1[o] + red[tid] + red[64 + tid] + red[128 + tid] + red[192 + tid];
            f1[gi * FF1 + o] = v > 0.f ? v : 0.f;
        }
    }
}

// ---------------------------------------------------------------------------
// K7: f2 += f1 @ W2  (K=1000 split over 16 blocks, atomic; c2 preloaded)
// ---------------------------------------------------------------------------
__global__ __launch_bounds__(256) void k_head2(
    const float* __restrict__ f1, const float* __restrict__ W2,
    float* __restrict__ f2)
{
    const int s = blockIdx.x;
    const int k0 = s * 63;
    const int kn = min(63, FF1 - k0);
    const int tid = threadIdx.x;
    __shared__ float f1s[4 * 63];
    for (int i = tid; i < 4 * kn; i += 256) {
        int gi = i / kn, kk = i - gi * kn;
        f1s[gi * 63 + kk] = f1[gi * FF1 + k0 + kk];
    }
    __syncthreads();
    for (int idx = tid; idx < GG * FF2; idx += 256) {
        int gi = idx / FF2, o = idx - gi * FF2;
        float acc = 0.f;
        for (int kk = 0; kk < kn; ++kk)
            acc += f1s[gi * 63 + kk] * W2[(k0 + kk) * FF2 + o];
        atomicAdd(&f2[idx], acc);
    }
}

// ---------------------------------------------------------------------------
// K8: f3 = relu(relu(f2) @ W3 + c3); out = f3 @ W4 + c4   (single tiny block)
// ---------------------------------------------------------------------------
__global__ __launch_bounds__(256) void k_head3(
    const float* __restrict__ f2, const float* __restrict__ W3,
    const float* __restrict__ c3, const float* __restrict__ W4,
    const float* __restrict__ c4, float* __restrict__ out)
{
    const int tid = threadIdx.x;
    __shared__ float f2s[GG * FF2];
    __shared__ float f3s[GG * FF3];
    for (int i = tid; i < GG * FF2; i += 256) {
        float v = f2[i];
        f2s[i] = v > 0.f ? v : 0.f;
    }
    __syncthreads();
    if (tid < GG * FF3) {
        int gi = tid / FF3, o = tid - gi * FF3;
        float acc = c3[o];
        for (int k = 0; k < FF2; ++k)
            acc += f2s[gi * FF2 + k] * W3[k * FF3 + o];
        f3s[tid] = acc > 0.f ? acc : 0.f;
    }
    __syncthreads();
    if (tid < GG) {
        float acc = c4[0];
        #pragma unroll
        for (int k = 0; k < FF3; ++k) acc += f3s[tid * FF3 + k] * W4[k];
        out[tid] = acc;
    }
}

extern "C" void kernel_launch(void* const* d_in, const int* in_sizes, int n_in,
                              void* d_out, int out_size, void* d_ws, size_t ws_size,
                              hipStream_t stream) {
    const float* x          = (const float*)d_in[0];
    const int*   edge_index = (const int*)  d_in[1];
    const float* edge_attr  = (const float*)d_in[2];
    const int*   batch      = (const int*)  d_in[3];
    const float* We1 = (const float*)d_in[4];
    const float* be1 = (const float*)d_in[5];
    const float* root1 = (const float*)d_in[6];
    const float* b1  = (const float*)d_in[7];
    const float* We2 = (const float*)d_in[8];
    const float* be2 = (const float*)d_in[9];
    const float* root2 = (const float*)d_in[10];
    const float* b2  = (const float*)d_in[11];
    const float* We3 = (const float*)d_in[12];
    const float* be3 = (const float*)d_in[13];
    const float* root3 = (const float*)d_in[14];
    const float* b3  = (const float*)d_in[15];
    const float* W1 = (const float*)d_in[16];
    const float* c1 = (const float*)d_in[17];
    const float* W2 = (const float*)d_in[18];
    const float* c2 = (const float*)d_in[19];
    const float* W3 = (const float*)d_in[20];
    const float* c3 = (const float*)d_in[21];
    const float* W4 = (const float*)d_in[22];
    const float* c4 = (const float*)d_in[23];
    float* ws  = (float*)d_ws;
    float* out = (float*)d_out;

    // K0: Ach + Y + f2=c2 preload
    k_init<<<3, 256, 0, stream>>>(x, edge_index, edge_attr, c2, ws);
    // K1: P1 = relu(b1 + Y @ Wall1)   [64x2000, K=54]
    k_lin1<<<32, 256, 0, stream>>>(ws + OFF_Y, We1, be1, root1, b1, ws + OFF_P1);
    // K2a: Q2f[64x12000] = A_d @ P1   (6 d x 16 k-tiles)
    k_q<2000, 12000, 16><<<96, 256, 0, stream>>>(ws + OFF_ACH, ws + OFF_P1,
                                                 ws + OFF_Q);
    // K2b: part[50][64x500] = Q2f @ Wstack2   (16 col-tiles x 50 K-slices)
    k_split<500, 16, 50, 12, 8000, 10000><<<800, 256, 0, stream>>>(
        ws + OFF_Q, We2, be2, root2, ws + OFF_PART);
    // K2c: P2 = relu(b2 + sum part)
    k_red2<<<32, 256, 0, stream>>>(ws + OFF_PART, b2, ws + OFF_P2);
    // K3a: Q3f[64x3000] = A_d @ P2   (6 d x 4 k-tiles)
    k_q<500, 3000, 4><<<24, 256, 0, stream>>>(ws + OFF_ACH, ws + OFF_P2,
                                              ws + OFF_Q);
    // K3b: part[50][64x100] = Q3f @ Wstack3   (4 col-tiles x 50 K-slices)
    k_split<100, 4, 50, 3, 2000, 2500><<<200, 256, 0, stream>>>(
        ws + OFF_Q, We3, be3, root3, ws + OFF_PART);
    // K3c: pre3 = b3 + sum part
    k_red3<<<7, 256, 0, stream>>>(ws + OFF_PART, b3, ws + OFF_PRE3);
    // K6: g + f1
    k_head1<<<64, 256, 0, stream>>>(ws + OFF_PRE3, batch, W1, c1, ws + OFF_F1);
    // K7: f2
    k_head2<<<16, 256, 0, stream>>>(ws + OFF_F1, W2, ws + OFF_F2);
    // K8: f3 + out
    k_head3<<<1, 256, 0, stream>>>(ws + OFF_F2, W3, c3, W4, c4, out);
}

// Round 3
// 216.492 us; speedup vs baseline: 1.5373x; 1.5373x over previous
//
#include <hip/hip_runtime.h>

// Problem dims
#define NN 64
#define EE 128
#define GG 4
#define D0 9
#define EDIM 4
#define H1 2000
#define H2 500
#define H3 100
#define FF1 1000
#define FF2 100
#define FF3 50

// Workspace layout (floats)
#define OFF_ACH  0         // 6*64*64 = 24576   per-channel adjacency A_d[v][u]
#define OFF_Y    24576     // 64*54   = 3456    folded layer-1 input
#define OFF_P1   28032     // 64*2000 = 128000  relu(pre1)
#define OFF_Q    156032    // 64*12000= 768000  Q2f (Q3f 64*3000 overlays)
#define OFF_PART 924032    // 50*64*500 = 1600000 partials (L3 50*64*100 overlays)
#define OFF_P2   2524032   // 64*500  = 32000   relu(pre2)
#define OFF_PRE3 2556032   // 64*100  = 6400
#define OFF_F1   2562432   // 4*1000  = 4000
#define OFF_F2   2566432   // 4*100   = 400
// total 2566832 floats = 10.3 MB

// ---------------------------------------------------------------------------
// async global->LDS 16B copy. LDS dest is wave-uniform base + lane*16;
// global source address is per-lane.
// ---------------------------------------------------------------------------
__device__ __forceinline__ void gl2lds16(const float* g, float* l) {
    __builtin_amdgcn_global_load_lds(
        (const __attribute__((address_space(1))) unsigned int*)g,
        (__attribute__((address_space(3))) unsigned int*)l,
        16, 0, 0);
}

__device__ __forceinline__ float4 ldf4(const float* p) {
    return *(const float4*)p;
}

// counted vmcnt wait (wave-uniform n). "memory" clobber = compiler fence.
__device__ __forceinline__ void waitcnt_vm_n(int n) {
    switch (n) {
    case 0: asm volatile("s_waitcnt vmcnt(0)" ::: "memory"); break;
    case 1: asm volatile("s_waitcnt vmcnt(1)" ::: "memory"); break;
    case 2: asm volatile("s_waitcnt vmcnt(2)" ::: "memory"); break;
    case 3: asm volatile("s_waitcnt vmcnt(3)" ::: "memory"); break;
    case 4: asm volatile("s_waitcnt vmcnt(4)" ::: "memory"); break;
    case 5: asm volatile("s_waitcnt vmcnt(5)" ::: "memory"); break;
    default: asm volatile("s_waitcnt vmcnt(6)" ::: "memory"); break;
    }
}
__device__ __forceinline__ void cfence() { asm volatile("" ::: "memory"); }

// ---------------------------------------------------------------------------
// K0: block0 = Ach (per-channel 64x64 adjacency), block1 = Y, block2 = f2=c2
// ---------------------------------------------------------------------------
__global__ __launch_bounds__(256) void k_init(
    const float* __restrict__ x, const int* __restrict__ edge_index,
    const float* __restrict__ edge_attr, const float* __restrict__ c2,
    float* __restrict__ ws)
{
    const int b = blockIdx.x, tid = threadIdx.x;
    if (b == 0) {
        // Ach[d][t][s]: d<4 edge_attr scatter; d=4 edge count; d=5 identity
        float* A = ws + OFF_ACH;
        for (int i = tid; i < 6 * NN * NN; i += 256) A[i] = 0.f;
        __syncthreads();
        if (tid < EE) {
            int s = edge_index[tid];
            int t = edge_index[EE + tid];
            #pragma unroll
            for (int d = 0; d < 4; ++d)
                atomicAdd(A + d * 4096 + t * 64 + s, edge_attr[tid * 4 + d]);
            atomicAdd(A + 4 * 4096 + t * 64 + s, 1.0f);
        }
        if (tid < NN) A[5 * 4096 + tid * 64 + tid] = 1.0f;
    } else if (b == 1) {
        // Y[u, d*9+i]: d<4 edge-weighted scatter of x[src], d=4 edge-count
        // scatter, d=5 identity (x itself)
        __shared__ float Ys[NN * 54];
        for (int i = tid; i < NN * 54; i += 256) Ys[i] = 0.f;
        __syncthreads();
        if (tid < EE) {
            int s = edge_index[tid];
            int t = edge_index[EE + tid];
            float ea[4];
            #pragma unroll
            for (int d = 0; d < 4; ++d) ea[d] = edge_attr[tid * 4 + d];
            #pragma unroll
            for (int i = 0; i < D0; ++i) {
                float xv = x[s * D0 + i];
                #pragma unroll
                for (int d = 0; d < 4; ++d)
                    atomicAdd(&Ys[t * 54 + d * 9 + i], ea[d] * xv);
                atomicAdd(&Ys[t * 54 + 36 + i], xv);
            }
        }
        if (tid < NN) {
            #pragma unroll
            for (int i = 0; i < D0; ++i) Ys[tid * 54 + 45 + i] = x[tid * D0 + i];
        }
        __syncthreads();
        for (int i = tid; i < NN * 54; i += 256) ws[OFF_Y + i] = Ys[i];
    } else {
        for (int i = tid; i < GG * FF2; i += 256) ws[OFF_F2 + i] = c2[i % FF2];
    }
}

// ---------------------------------------------------------------------------
// K1: P1[64x2000] = relu(b1 + Y[64x54] @ Wall1[54x2000])
// ---------------------------------------------------------------------------
__global__ __launch_bounds__(256) void k_lin1(
    const float* __restrict__ Yw,
    const float* __restrict__ We1, const float* __restrict__ be1,
    const float* __restrict__ root1, const float* __restrict__ b1,
    float* __restrict__ pre1)
{
    const int tid = threadIdx.x;
    const int tx = tid & 15, ty = tid >> 4;
    const int o0 = blockIdx.x * 64;
    const int w = min(64, H1 - o0);

    __shared__ float Ys[64 * 56];
    __shared__ __align__(16) float Bs[54 * 64];

    for (int i = tid; i < 64 * 54; i += 256) {
        int u = i / 54, r = i - u * 54;
        Ys[u * 56 + r] = Yw[i];
    }
    for (int i = tid; i < 54 * 64; i += 256) {
        int r = i >> 6, c = i & 63;
        int d = r / 9, ii = r - d * 9;
        const float* rowp = ((d < 4) ? (We1 + d * (D0 * H1))
                                     : ((d == 4) ? be1 : root1)) + ii * H1;
        Bs[r * 64 + c] = (c < w) ? rowp[o0 + c] : 0.f;
    }
    __syncthreads();

    float acc[4][4] = {};
    #pragma unroll 6
    for (int r = 0; r < 54; ++r) {
        float a0 = Ys[(ty * 4 + 0) * 56 + r];
        float a1 = Ys[(ty * 4 + 1) * 56 + r];
        float a2 = Ys[(ty * 4 + 2) * 56 + r];
        float a3 = Ys[(ty * 4 + 3) * 56 + r];
        const float4 bv = *(const float4*)&Bs[r * 64 + tx * 4];
        acc[0][0] += a0 * bv.x; acc[0][1] += a0 * bv.y; acc[0][2] += a0 * bv.z; acc[0][3] += a0 * bv.w;
        acc[1][0] += a1 * bv.x; acc[1][1] += a1 * bv.y; acc[1][2] += a1 * bv.z; acc[1][3] += a1 * bv.w;
        acc[2][0] += a2 * bv.x; acc[2][1] += a2 * bv.y; acc[2][2] += a2 * bv.z; acc[2][3] += a2 * bv.w;
        acc[3][0] += a3 * bv.x; acc[3][1] += a3 * bv.y; acc[3][2] += a3 * bv.z; acc[3][3] += a3 * bv.w;
    }
    #pragma unroll
    for (int i = 0; i < 4; ++i) {
        int u = ty * 4 + i;
        #pragma unroll
        for (int jj = 0; jj < 4; ++jj) {
            int j = o0 + tx * 4 + jj;
            if (j < H1) {
                float v = b1[j] + acc[i][jj];
                pre1[u * H1 + j] = v > 0.f ? v : 0.f;
            }
        }
    }
}

// ---------------------------------------------------------------------------
// k_q: Qf[v, d*Kd + k] = sum_u Ach[d][v][u] * P[u][k]
//   block = (d, kt): 128 P-cols. A_d (16KB) AND P-tile (32KB) staged in LDS.
//   thread = (col-quad kq 0..31, row-group rg 0..7 of 8 rows); acc[8][4];
//   all inner-loop operands via ds_read_b128 (A reads wave-broadcast).
// ---------------------------------------------------------------------------
template<int Kd, int KTOT, int NKT>
__global__ __launch_bounds__(256) void k_q(
    const float* __restrict__ Ach, const float* __restrict__ P,
    float* __restrict__ Qf)
{
    const int bx = blockIdx.x;
    const int d = bx / NKT, kt = bx % NKT;
    const int k0 = kt * 128;
    const int tid = threadIdx.x;
    const int kq = tid & 31;          // column quad (4 floats)
    const int rg = tid >> 5;          // row group (8 rows each)
    const int nf4 = (min(128, Kd - k0) + 3) >> 2;

    __shared__ __align__(16) float Al[64 * 64];     // A_d[v][u]
    __shared__ __align__(16) float Pl[64 * 128];    // P[u][k-k0]

    const float* Ad = Ach + d * 4096;
    for (int i4 = tid; i4 < 1024; i4 += 256)
        *(float4*)&Al[i4 * 4] = ldf4(Ad + i4 * 4);
    for (int i4 = tid; i4 < 64 * 32; i4 += 256) {
        int u = i4 >> 5, c4 = i4 & 31;
        float4 v = {0.f, 0.f, 0.f, 0.f};
        if (c4 < nf4) v = ldf4(P + u * Kd + k0 + c4 * 4);
        *(float4*)&Pl[u * 128 + c4 * 4] = v;
    }
    __syncthreads();

    float acc[8][4] = {};
    #pragma unroll 4
    for (int u4 = 0; u4 < 16; ++u4) {
        float4 pv0 = ldf4(&Pl[(u4 * 4 + 0) * 128 + kq * 4]);
        float4 pv1 = ldf4(&Pl[(u4 * 4 + 1) * 128 + kq * 4]);
        float4 pv2 = ldf4(&Pl[(u4 * 4 + 2) * 128 + kq * 4]);
        float4 pv3 = ldf4(&Pl[(u4 * 4 + 3) * 128 + kq * 4]);
        #pragma unroll
        for (int i = 0; i < 8; ++i) {
            float4 a = ldf4(&Al[(rg * 8 + i) * 64 + u4 * 4]);
            acc[i][0] += a.x * pv0.x + a.y * pv1.x + a.z * pv2.x + a.w * pv3.x;
            acc[i][1] += a.x * pv0.y + a.y * pv1.y + a.z * pv2.y + a.w * pv3.y;
            acc[i][2] += a.x * pv0.z + a.y * pv1.z + a.z * pv2.z + a.w * pv3.z;
            acc[i][3] += a.x * pv0.w + a.y * pv1.w + a.z * pv2.w + a.w * pv3.w;
        }
    }
    const int k = k0 + kq * 4;
    if (k < Kd) {
        #pragma unroll
        for (int i = 0; i < 8; ++i) {
            int r = rg * 8 + i;
            *(float4*)(Qf + r * KTOT + d * Kd + k) =
                make_float4(acc[i][0], acc[i][1], acc[i][2], acc[i][3]);
        }
    }
}

// ---------------------------------------------------------------------------
// k_split: part[s][64][M] (col stripe o0..o0+31) = Qf[64 x span] @ Wstk
//   Wstk rows kg: [0,T1) We (flat), [T1,T2) be, [T2,KTOT) root.
//   NON-ATOMIC output (slice per K-span). BN=32, KC=20.
//   Counted-vmcnt double-buffer: raw s_barrier + per-wave vmcnt(n) keeps the
//   next-tile global_load_lds prefetch in flight ACROSS the barrier (no
//   __syncthreads vmcnt(0) drain). B-tail uses address clamping (not lane
//   masks) so per-wave VMEM issue counts are deterministic.
// ---------------------------------------------------------------------------
template<int M, int OT, int S, int ITERS, int T1, int T2>
__global__ __launch_bounds__(256) void k_split(
    const float* __restrict__ Qf, const float* __restrict__ We,
    const float* __restrict__ be, const float* __restrict__ root,
    float* __restrict__ part)
{
    constexpr int KC = 20, BN = 32;
    constexpr int KTOT = S * ITERS * KC;
    constexpr int AC = (64 * KC) / 256;             // A chunks (5)
    constexpr int BFL = KC * BN;                    // B floats (640)
    constexpr int BC = (BFL + 255) / 256;           // B chunks (3)
    const int b = blockIdx.x;
    const int s = b % S, ot = b / S;
    const int o0 = ot * BN;
    const int tid = threadIdx.x;
    const int tx = tid & 7, ty = tid >> 3;          // 8 col-quads x 32 row-pairs
    const int wv = tid >> 6, ln = tid & 63;
    const int kbase = s * (KC * ITERS);
    // per-wave VMEM issue count per stage()
    const int nw = ((AC - wv + 3) >> 2) + ((wv < BC) ? ((BC - wv + 3) >> 2) : 0);

    __shared__ __align__(16) float As[2][64 * KC];   // [row][k]
    __shared__ __align__(16) float Bs[2][KC * BN];   // [k][col]

    auto stage = [&](int bf, int kb) {
        for (int c = wv; c < AC; c += 4) {
            int f = c * 256 + ln * 4;
            int r = f / KC, kkk = f - r * KC;
            gl2lds16(Qf + r * KTOT + kb + kkk, &As[bf][c * 256]);
        }
        for (int c = wv; c < BC; c += 4) {
            int f = c * 256 + ln * 4;
            if (f < BFL) {                           // lane mask; >=1 lane live
                int krow = f / BN, col = f - krow * BN;
                int kg = kb + krow;
                const float* bp = (kg < T1) ? (We + (long long)kg * M)
                                : (kg < T2) ? (be + (long long)(kg - T1) * M)
                                            : (root + (long long)(kg - T2) * M);
                int cc = min(o0 + col, M - 4);       // clamp, stays 16B-aligned
                gl2lds16(bp + cc, &Bs[bf][c * 256]);
            }
        }
    };

    float acc[2][4] = {};
    stage(0, kbase);

    for (int it = 0; it < ITERS; ++it) {
        int npend = 0;
        if (it + 1 < ITERS) { stage((it + 1) & 1, kbase + (it + 1) * KC); npend = nw; }
        waitcnt_vm_n(npend);                 // own current-buf loads done
        __builtin_amdgcn_s_barrier();        // all waves' writes visible
        __builtin_amdgcn_sched_barrier(0);

        const float* Ab = As[it & 1];
        const float* Bb = Bs[it & 1];
        #pragma unroll
        for (int k4 = 0; k4 < KC / 4; ++k4) {
            float4 a0 = ldf4(&Ab[(ty * 2 + 0) * KC + k4 * 4]);
            float4 a1 = ldf4(&Ab[(ty * 2 + 1) * KC + k4 * 4]);
            float4 b0 = ldf4(&Bb[(k4 * 4 + 0) * BN + tx * 4]);
            float4 b1 = ldf4(&Bb[(k4 * 4 + 1) * BN + tx * 4]);
            float4 b2 = ldf4(&Bb[(k4 * 4 + 2) * BN + tx * 4]);
            float4 b3 = ldf4(&Bb[(k4 * 4 + 3) * BN + tx * 4]);
            acc[0][0] += a0.x * b0.x; acc[0][1] += a0.x * b0.y; acc[0][2] += a0.x * b0.z; acc[0][3] += a0.x * b0.w;
            acc[0][0] += a0.y * b1.x; acc[0][1] += a0.y * b1.y; acc[0][2] += a0.y * b1.z; acc[0][3] += a0.y * b1.w;
            acc[0][0] += a0.z * b2.x; acc[0][1] += a0.z * b2.y; acc[0][2] += a0.z * b2.z; acc[0][3] += a0.z * b2.w;
            acc[0][0] += a0.w * b3.x; acc[0][1] += a0.w * b3.y; acc[0][2] += a0.w * b3.z; acc[0][3] += a0.w * b3.w;
            acc[1][0] += a1.x * b0.x; acc[1][1] += a1.x * b0.y; acc[1][2] += a1.x * b0.z; acc[1][3] += a1.x * b0.w;
            acc[1][0] += a1.y * b1.x; acc[1][1] += a1.y * b1.y; acc[1][2] += a1.y * b1.z; acc[1][3] += a1.y * b1.w;
            acc[1][0] += a1.z * b2.x; acc[1][1] += a1.z * b2.y; acc[1][2] += a1.z * b2.z; acc[1][3] += a1.z * b2.w;
            acc[1][0] += a1.w * b3.x; acc[1][1] += a1.w * b3.y; acc[1][2] += a1.w * b3.z; acc[1][3] += a1.w * b3.w;
        }
        cfence();
        __builtin_amdgcn_sched_barrier(0);
        __builtin_amdgcn_s_barrier();        // reads done before next overwrite
    }

    float* dst = part + s * (64 * M);
    #pragma unroll
    for (int i = 0; i < 2; ++i) {
        int u = ty * 2 + i;
        #pragma unroll
        for (int jj = 0; jj < 4; ++jj) {
            int j = o0 + tx * 4 + jj;
            if (j < M) dst[u * M + j] = acc[i][jj];
        }
    }
}

// ---------------------------------------------------------------------------
// k_red2: P2 = relu(b2 + sum_s part[s])   [64x500], 50 slices
// ---------------------------------------------------------------------------
__global__ __launch_bounds__(256) void k_red2(
    const float* __restrict__ part, const float* __restrict__ b2,
    float* __restrict__ P2)
{
    int i4 = blockIdx.x * 256 + threadIdx.x;
    if (i4 >= (64 * 500) / 4) return;
    int o = (i4 * 4) % 500;
    float4 acc = ldf4(b2 + o);
    #pragma unroll 10
    for (int s = 0; s < 50; ++s) {
        float4 v = ldf4(part + s * 32000 + i4 * 4);
        acc.x += v.x; acc.y += v.y; acc.z += v.z; acc.w += v.w;
    }
    acc.x = fmaxf(acc.x, 0.f); acc.y = fmaxf(acc.y, 0.f);
    acc.z = fmaxf(acc.z, 0.f); acc.w = fmaxf(acc.w, 0.f);
    *(float4*)(P2 + i4 * 4) = acc;
}

// ---------------------------------------------------------------------------
// k_red3: pre3 = b3 + sum_s part[s]   [64x100], 50 slices (raw; relu in head1)
// ---------------------------------------------------------------------------
__global__ __launch_bounds__(256) void k_red3(
    const float* __restrict__ part, const float* __restrict__ b3,
    float* __restrict__ pre3)
{
    int i4 = blockIdx.x * 256 + threadIdx.x;
    if (i4 >= (64 * 100) / 4) return;
    int o = (i4 * 4) % 100;
    float4 acc = ldf4(b3 + o);
    #pragma unroll 10
    for (int s = 0; s < 50; ++s) {
        float4 v = ldf4(part + s * 6400 + i4 * 4);
        acc.x += v.x; acc.y += v.y; acc.z += v.z; acc.w += v.w;
    }
    *(float4*)(pre3 + i4 * 4) = acc;
}

// ---------------------------------------------------------------------------
// K6: per (gi, o-tile) block: g[gi] = segment-sum relu(pre3), then
//     f1[gi, o-tile] = relu(c1 + g @ W1)
// ---------------------------------------------------------------------------
__global__ __launch_bounds__(256) void k_head1(
    const float* __restrict__ pre3, const int* __restrict__ batch,
    const float* __restrict__ W1, const float* __restrict__ c1,
    float* __restrict__ f1)
{
    const int gi = blockIdx.x >> 4;
    const int jt = blockIdx.x & 15;
    const int o0 = jt * 64;
    const int tid = threadIdx.x;
    __shared__ int   bsh[NN];
    __shared__ float gs[H3];
    __shared__ float red[4 * 64];

    if (tid < NN) bsh[tid] = batch[tid];
    __syncthreads();
    for (int d = tid; d < H3; d += 256) {
        float acc = 0.f;
        #pragma unroll
        for (int v = 0; v < NN; ++v) {
            float h = pre3[v * H3 + d];
            h = h > 0.f ? h : 0.f;
            acc += (bsh[v] == gi) ? h : 0.f;
        }
        gs[d] = acc;
    }
    __syncthreads();
    const int jj = tid & 63, kq = tid >> 6;
    const int oc = min(o0 + jj, FF1 - 1);
    float p = 0.f;
    #pragma unroll
    for (int k = kq * 25; k < kq * 25 + 25; ++k)
        p += gs[k] * W1[k * FF1 + oc];
    red[kq * 64 + jj] = p;
    __syncthreads();
    if (tid < 64) {
        int o = o0 + tid;
        if (o < FF1) {
            float v = c1[o] + red[tid] + red[64 + tid] + red[128 + tid] + red[192 + tid];
            f1[gi * FF1 + o] = v > 0.f ? v : 0.f;
        }
    }
}

// ---------------------------------------------------------------------------
// K7: f2 += f1 @ W2  (K=1000 split over 16 blocks, atomic; c2 preloaded)
// ---------------------------------------------------------------------------
__global__ __launch_bounds__(256) void k_head2(
    const float* __restrict__ f1, const float* __restrict__ W2,
    float* __restrict__ f2)
{
    const int s = blockIdx.x;
    const int k0 = s * 63;
    const int kn = min(63, FF1 - k0);
    const int tid = threadIdx.x;
    __shared__ float f1s[4 * 63];
    for (int i = tid; i < 4 * kn; i += 256) {
        int gi = i / kn, kk = i - gi * kn;
        f1s[gi * 63 + kk] = f1[gi * FF1 + k0 + kk];
    }
    __syncthreads();
    for (int idx = tid; idx < GG * FF2; idx += 256) {
        int gi = idx / FF2, o = idx - gi * FF2;
        float acc = 0.f;
        for (int kk = 0; kk < kn; ++kk)
            acc += f1s[gi * 63 + kk] * W2[(k0 + kk) * FF2 + o];
        atomicAdd(&f2[idx], acc);
    }
}

// ---------------------------------------------------------------------------
// K8: f3 = relu(relu(f2) @ W3 + c3); out = f3 @ W4 + c4   (single tiny block)
// ---------------------------------------------------------------------------
__global__ __launch_bounds__(256) void k_head3(
    const float* __restrict__ f2, const float* __restrict__ W3,
    const float* __restrict__ c3, const float* __restrict__ W4,
    const float* __restrict__ c4, float* __restrict__ out)
{
    const int tid = threadIdx.x;
    __shared__ float f2s[GG * FF2];
    __shared__ float f3s[GG * FF3];
    for (int i = tid; i < GG * FF2; i += 256) {
        float v = f2[i];
        f2s[i] = v > 0.f ? v : 0.f;
    }
    __syncthreads();
    if (tid < GG * FF3) {
        int gi = tid / FF3, o = tid - gi * FF3;
        float acc = c3[o];
        for (int k = 0; k < FF2; ++k)
            acc += f2s[gi * FF2 + k] * W3[k * FF3 + o];
        f3s[tid] = acc > 0.f ? acc : 0.f;
    }
    __syncthreads();
    if (tid < GG) {
        float acc = c4[0];
        #pragma unroll
        for (int k = 0; k < FF3; ++k) acc += f3s[tid * FF3 + k] * W4[k];
        out[tid] = acc;
    }
}

extern "C" void kernel_launch(void* const* d_in, const int* in_sizes, int n_in,
                              void* d_out, int out_size, void* d_ws, size_t ws_size,
                              hipStream_t stream) {
    const float* x          = (const float*)d_in[0];
    const int*   edge_index = (const int*)  d_in[1];
    const float* edge_attr  = (const float*)d_in[2];
    const int*   batch      = (const int*)  d_in[3];
    const float* We1 = (const float*)d_in[4];
    const float* be1 = (const float*)d_in[5];
    const float* root1 = (const float*)d_in[6];
    const float* b1  = (const float*)d_in[7];
    const float* We2 = (const float*)d_in[8];
    const float* be2 = (const float*)d_in[9];
    const float* root2 = (const float*)d_in[10];
    const float* b2  = (const float*)d_in[11];
    const float* We3 = (const float*)d_in[12];
    const float* be3 = (const float*)d_in[13];
    const float* root3 = (const float*)d_in[14];
    const float* b3  = (const float*)d_in[15];
    const float* W1 = (const float*)d_in[16];
    const float* c1 = (const float*)d_in[17];
    const float* W2 = (const float*)d_in[18];
    const float* c2 = (const float*)d_in[19];
    const float* W3 = (const float*)d_in[20];
    const float* c3 = (const float*)d_in[21];
    const float* W4 = (const float*)d_in[22];
    const float* c4 = (const float*)d_in[23];
    float* ws  = (float*)d_ws;
    float* out = (float*)d_out;

    // K0: Ach + Y + f2=c2 preload
    k_init<<<3, 256, 0, stream>>>(x, edge_index, edge_attr, c2, ws);
    // K1: P1 = relu(b1 + Y @ Wall1)   [64x2000, K=54]
    k_lin1<<<32, 256, 0, stream>>>(ws + OFF_Y, We1, be1, root1, b1, ws + OFF_P1);
    // K2a: Q2f[64x12000] = A_d @ P1   (6 d x 16 k-tiles)
    k_q<2000, 12000, 16><<<96, 256, 0, stream>>>(ws + OFF_ACH, ws + OFF_P1,
                                                 ws + OFF_Q);
    // K2b: part[50][64x500] = Q2f @ Wstack2   (16 col-tiles x 50 K-slices)
    k_split<500, 16, 50, 12, 8000, 10000><<<800, 256, 0, stream>>>(
        ws + OFF_Q, We2, be2, root2, ws + OFF_PART);
    // K2c: P2 = relu(b2 + sum part)
    k_red2<<<32, 256, 0, stream>>>(ws + OFF_PART, b2, ws + OFF_P2);
    // K3a: Q3f[64x3000] = A_d @ P2   (6 d x 4 k-tiles)
    k_q<500, 3000, 4><<<24, 256, 0, stream>>>(ws + OFF_ACH, ws + OFF_P2,
                                              ws + OFF_Q);
    // K3b: part[50][64x100] = Q3f @ Wstack3   (4 col-tiles x 50 K-slices)
    k_split<100, 4, 50, 3, 2000, 2500><<<200, 256, 0, stream>>>(
        ws + OFF_Q, We3, be3, root3, ws + OFF_PART);
    // K3c: pre3 = b3 + sum part
    k_red3<<<7, 256, 0, stream>>>(ws + OFF_PART, b3, ws + OFF_PRE3);
    // K6: g + f1
    k_head1<<<64, 256, 0, stream>>>(ws + OFF_PRE3, batch, W1, c1, ws + OFF_F1);
    // K7: f2
    k_head2<<<16, 256, 0, stream>>>(ws + OFF_F1, W2, ws + OFF_F2);
    // K8: f3 + out
    k_head3<<<1, 256, 0, stream>>>(ws + OFF_F2, W3, c3, W4, c4, out);
}